// Round 1
// 202.239 us; speedup vs baseline: 1.0437x; 1.0437x over previous
//
#include <hip/hip_runtime.h>

// IoU distance: out[i][j] = inter/union + 1e-16, lhs (N,2), rhs (512,2), out (N,512) fp32.
//
// Structure: one wave per output row (grid-stride over rows). Each lane owns 8
// fixed columns: [4*lane, 4*lane+4) and [256+4*lane, 256+4*lane+4), so each of
// the wave's two float4 stores is a contiguous 1 KiB line-aligned burst.
// rhs (4 KB) is loaded ONCE per thread into registers (rw/rh/rw*rh precomputed),
// amortized over ~12 rows. Row index is wave-uniform (readfirstlane) so the lhs
// load and the output-row base address are scalar (s_load + saddr stores).
// ~6 VALU/element, v_rcp_f32 instead of IEEE div (absmax threshold 2e-2).
//
// R1 change: plain stores instead of __builtin_nontemporal_store. Output is
// 204.8 MB < 256 MB Infinity Cache; nt bypassed L2/L3 and pinned every line's
// HBM write onto the kernel's critical path (~2.4 TB/s observed). Plain stores
// land in L2->L3 at cache speed; dirty writeback is deferred/elided (the next
// poison fill re-dirties the same lines in place).

#define NCOLS 512

typedef float vfloat4 __attribute__((ext_vector_type(4)));

__global__ __launch_bounds__(256) void iou_kernel(
    const float2* __restrict__ lhs,
    const float*  __restrict__ rhs,
    float* __restrict__ out,
    int n_rows, int total_waves)
{
    const int tid  = blockIdx.x * blockDim.x + threadIdx.x;
    const int lane = threadIdx.x & 63;
    const int wave = __builtin_amdgcn_readfirstlane(tid >> 6);

    // Preload this lane's 8 columns of rhs into registers.
    // rhs4[c2] = {w[2c2], h[2c2], w[2c2+1], h[2c2+1]}
    const vfloat4* rhs4 = (const vfloat4*)rhs;
    vfloat4 a0 = rhs4[2 * lane];          // cols 4*lane, 4*lane+1
    vfloat4 a1 = rhs4[2 * lane + 1];      // cols 4*lane+2, 4*lane+3
    vfloat4 b0 = rhs4[128 + 2 * lane];    // cols 256+4*lane, ...
    vfloat4 b1 = rhs4[128 + 2 * lane + 1];

    float rw[8] = {a0.x, a0.z, a1.x, a1.z, b0.x, b0.z, b1.x, b1.z};
    float rh[8] = {a0.y, a0.w, a1.y, a1.w, b0.y, b0.w, b1.y, b1.w};
    float ra[8];
#pragma unroll
    for (int k = 0; k < 8; ++k) ra[k] = rw[k] * rh[k];

    for (int row = wave; row < n_rows; row += total_waves) {
        float2 l = lhs[row];             // wave-uniform -> scalar load
        float la = l.x * l.y;

        float o[8];
#pragma unroll
        for (int k = 0; k < 8; ++k) {
            float inter = fminf(l.x, rw[k]) * fminf(l.y, rh[k]);
            float uni   = (la + ra[k]) - inter;
            o[k] = fmaf(inter, __builtin_amdgcn_rcpf(uni), 1e-16f);
        }

        vfloat4* orow = (vfloat4*)(out + (size_t)row * NCOLS);
        vfloat4 v0 = {o[0], o[1], o[2], o[3]};
        vfloat4 v1 = {o[4], o[5], o[6], o[7]};
        orow[lane]      = v0;            // cols 0..255, contiguous 1 KiB/wave
        orow[64 + lane] = v1;            // cols 256..511
    }
}

extern "C" void kernel_launch(void* const* d_in, const int* in_sizes, int n_in,
                              void* d_out, int out_size, void* d_ws, size_t ws_size,
                              hipStream_t stream) {
    const float2* lhs = (const float2*)d_in[0];
    const float*  rhs = (const float*)d_in[1];
    float* out = (float*)d_out;

    int n_rows = in_sizes[0] / 2;    // 100000

    // 2048 blocks x 4 waves = 8192 waves; low VGPR use -> full occupancy,
    // each wave handles ~12 rows.
    int blocks = 2048;
    int total_waves = blocks * (256 / 64);
    iou_kernel<<<blocks, 256, 0, stream>>>(lhs, rhs, out, n_rows, total_waves);
}

// Round 2
// 202.189 us; speedup vs baseline: 1.0439x; 1.0002x over previous
//
#include <hip/hip_runtime.h>

// IoU distance: out[i][j] = inter/union + 1e-16, lhs (N,2), rhs (512,2), out (N,512) fp32.
//
// Structure (R2): one wave per 4 CONSECUTIVE output rows (grid-stride over
// 4-row blocks). Each lane owns 8 fixed columns: [4*lane, 4*lane+4) and
// [256+4*lane, 256+4*lane+4), so every float4 store is a contiguous 1 KiB
// line-aligned burst; a wave's iteration writes 8 KB contiguous (4 rows).
//
// Why 4-row blocking (R2): R1 profile showed the kernel at ~2.7 TB/s store BW
// while the harness fill hits 6.5 TB/s on the same buffer. Old loop had only
// 2 outstanding stores between loop-carried scalar-load stalls, and waves
// wrote scattered 2 KB chunks (row stride = 8192 rows). Now: one 32 B scalar
// fetch covers 4 rows' lhs, compute 32 outputs, then 8 back-to-back dwordx4
// stores (4x the MLP, 4x the DRAM page locality, 1/4 the scalar-load stalls).
//
// rhs (4 KB) is loaded ONCE per thread into registers (rw/rh/rw*rh precomputed).
// Row-block index is wave-uniform (readfirstlane) so lhs loads are scalar and
// the output base address is scalar (saddr stores). v_rcp_f32 instead of IEEE
// div (absmax threshold 2e-2).

#define NCOLS 512
#define ROWS_PER_ITER 4

typedef float vfloat4 __attribute__((ext_vector_type(4)));

__global__ __launch_bounds__(256) void iou_kernel(
    const float2* __restrict__ lhs,
    const float*  __restrict__ rhs,
    float* __restrict__ out,
    int n_rows, int total_waves)
{
    const int tid  = blockIdx.x * blockDim.x + threadIdx.x;
    const int lane = threadIdx.x & 63;
    const int wave = __builtin_amdgcn_readfirstlane(tid >> 6);

    // Preload this lane's 8 columns of rhs into registers.
    // rhs4[c2] = {w[2c2], h[2c2], w[2c2+1], h[2c2+1]}
    const vfloat4* rhs4 = (const vfloat4*)rhs;
    vfloat4 a0 = rhs4[2 * lane];          // cols 4*lane, 4*lane+1
    vfloat4 a1 = rhs4[2 * lane + 1];      // cols 4*lane+2, 4*lane+3
    vfloat4 b0 = rhs4[128 + 2 * lane];    // cols 256+4*lane, ...
    vfloat4 b1 = rhs4[128 + 2 * lane + 1];

    float rw[8] = {a0.x, a0.z, a1.x, a1.z, b0.x, b0.z, b1.x, b1.z};
    float rh[8] = {a0.y, a0.w, a1.y, a1.w, b0.y, b0.w, b1.y, b1.w};
    float ra[8];
#pragma unroll
    for (int k = 0; k < 8; ++k) ra[k] = rw[k] * rh[k];

    // Grid-stride over 4-row blocks; n_rows = 100000 is divisible by 4.
    for (int base = wave * ROWS_PER_ITER; base < n_rows;
         base += total_waves * ROWS_PER_ITER) {

        // 4 consecutive rows' lhs: 32 contiguous bytes, wave-uniform ->
        // scalar loads (compiler emits s_load_dwordx4 pairs / dwordx8).
        float2 l[ROWS_PER_ITER];
#pragma unroll
        for (int r = 0; r < ROWS_PER_ITER; ++r) l[r] = lhs[base + r];

        // Compute all 32 outputs first, then store back-to-back so 8
        // dwordx4 stores are outstanding together.
        vfloat4 v[ROWS_PER_ITER][2];
#pragma unroll
        for (int r = 0; r < ROWS_PER_ITER; ++r) {
            const float lw = l[r].x, lh = l[r].y;
            const float la = lw * lh;
            float o[8];
#pragma unroll
            for (int k = 0; k < 8; ++k) {
                float inter = fminf(lw, rw[k]) * fminf(lh, rh[k]);
                float uni   = (la + ra[k]) - inter;
                o[k] = fmaf(inter, __builtin_amdgcn_rcpf(uni), 1e-16f);
            }
            v[r][0] = (vfloat4){o[0], o[1], o[2], o[3]};
            v[r][1] = (vfloat4){o[4], o[5], o[6], o[7]};
        }

        vfloat4* obase = (vfloat4*)(out + (size_t)base * NCOLS);
#pragma unroll
        for (int r = 0; r < ROWS_PER_ITER; ++r) {
            obase[r * 128 + lane]      = v[r][0];   // cols 0..255
            obase[r * 128 + 64 + lane] = v[r][1];   // cols 256..511
        }
    }
}

extern "C" void kernel_launch(void* const* d_in, const int* in_sizes, int n_in,
                              void* d_out, int out_size, void* d_ws, size_t ws_size,
                              hipStream_t stream) {
    const float2* lhs = (const float2*)d_in[0];
    const float*  rhs = (const float*)d_in[1];
    float* out = (float*)d_out;

    int n_rows = in_sizes[0] / 2;    // 100000

    // 2048 blocks x 4 waves = 8192 waves; low VGPR use -> full occupancy,
    // each wave handles ~3 blocks of 4 rows.
    int blocks = 2048;
    int total_waves = blocks * (256 / 64);
    iou_kernel<<<blocks, 256, 0, stream>>>(lhs, rhs, out, n_rows, total_waves);
}

// Round 3
// 199.885 us; speedup vs baseline: 1.0560x; 1.0115x over previous
//
#include <hip/hip_runtime.h>

// IoU distance: out[i][j] = inter/union + 1e-16, lhs (N,2), rhs (512,2), out (N,512) fp32.
//
// Structure (R3): STATIC schedule. 8336 waves, each wave owns exactly
// KITERS=3 blocks of 4 consecutive rows: blocks {w, w+8336, w+2*8336},
// out-of-range block ids clamped to the last block (the few clamped waves
// rewrite identical data -- branch-free tail, no divergence).
//
// Why (R3): R1/R2 falsified store-MLP and page-locality as limiters (both
// neutral). Remaining theory for the kernel running at ~2.6 TB/s vs the
// fill's 6.6: (a) runtime-trip-count grid-stride loop -> compiler can't
// unroll across iterations, so each iteration pays a full s_load+lgkmcnt(0)
// stall before its 8 stores; (b) 25000 blocks / 8192 waves = 3.05 -> 424
// straggler waves do a 4th iteration (+31% on the critical wave). With a
// compile-time trip count of 3 and clamped (unguarded) block ids, all 12
// lhs scalar loads hoist to kernel entry and all 24 dwordx4 stores stream
// back-to-back; every wave does identical work.
//
// Each lane owns 8 fixed columns: [4*lane, 4*lane+4) and [256+4*lane, ...),
// so every float4 store is a contiguous 1 KiB line-aligned wave burst.
// rhs (4 KB) loaded once per thread into registers. v_rcp_f32 instead of
// IEEE div (absmax threshold 2e-2).

#define NCOLS 512
#define RPB 4        // rows per block
#define KITERS 3     // blocks per wave (compile-time)

typedef float vfloat4 __attribute__((ext_vector_type(4)));

__global__ __launch_bounds__(256) void iou_kernel(
    const float2* __restrict__ lhs,
    const float*  __restrict__ rhs,
    float* __restrict__ out,
    int n_blocks, int total_waves)
{
    const int lane = threadIdx.x & 63;
    const int wave = __builtin_amdgcn_readfirstlane(
        (int)(blockIdx.x * blockDim.x + threadIdx.x) >> 6);

    // Preload this lane's 8 columns of rhs into registers.
    const vfloat4* rhs4 = (const vfloat4*)rhs;
    vfloat4 a0 = rhs4[2 * lane];
    vfloat4 a1 = rhs4[2 * lane + 1];
    vfloat4 b0 = rhs4[128 + 2 * lane];
    vfloat4 b1 = rhs4[128 + 2 * lane + 1];

    float rw[8] = {a0.x, a0.z, a1.x, a1.z, b0.x, b0.z, b1.x, b1.z};
    float rh[8] = {a0.y, a0.w, a1.y, a1.w, b0.y, b0.w, b1.y, b1.w};
    float ra[8];
#pragma unroll
    for (int k = 0; k < 8; ++k) ra[k] = rw[k] * rh[k];

    // Wave-uniform block ids, clamped (no guards -> loads hoistable).
    int blk[KITERS];
#pragma unroll
    for (int k = 0; k < KITERS; ++k) {
        int b = wave + k * total_waves;
        blk[k] = (b < n_blocks) ? b : (n_blocks - 1);
    }

    // All lhs scalar loads issued up front (wave-uniform -> s_load, no
    // loop-carried lgkmcnt stalls).
    float2 l[KITERS][RPB];
#pragma unroll
    for (int k = 0; k < KITERS; ++k)
#pragma unroll
        for (int r = 0; r < RPB; ++r)
            l[k][r] = lhs[blk[k] * RPB + r];

    // Compute + stream all 24 dwordx4 stores.
#pragma unroll
    for (int k = 0; k < KITERS; ++k) {
        vfloat4* obase = (vfloat4*)(out + (size_t)blk[k] * RPB * NCOLS);
#pragma unroll
        for (int r = 0; r < RPB; ++r) {
            const float lw = l[k][r].x, lh = l[k][r].y;
            const float la = lw * lh;
            float o[8];
#pragma unroll
            for (int j = 0; j < 8; ++j) {
                float inter = fminf(lw, rw[j]) * fminf(lh, rh[j]);
                float uni   = (la + ra[j]) - inter;
                o[j] = fmaf(inter, __builtin_amdgcn_rcpf(uni), 1e-16f);
            }
            vfloat4 v0 = {o[0], o[1], o[2], o[3]};
            vfloat4 v1 = {o[4], o[5], o[6], o[7]};
            obase[r * 128 + lane]      = v0;   // cols 0..255
            obase[r * 128 + 64 + lane] = v1;   // cols 256..511
        }
    }
}

extern "C" void kernel_launch(void* const* d_in, const int* in_sizes, int n_in,
                              void* d_out, int out_size, void* d_ws, size_t ws_size,
                              hipStream_t stream) {
    const float2* lhs = (const float2*)d_in[0];
    const float*  rhs = (const float*)d_in[1];
    float* out = (float*)d_out;

    int n_rows   = in_sizes[0] / 2;            // 100000
    int n_blocks = (n_rows + RPB - 1) / RPB;   // 25000

    // waves needed so KITERS iterations cover all blocks:
    // total_waves = ceil(n_blocks / KITERS), rounded up to 4 waves/block.
    int waves_needed = (n_blocks + KITERS - 1) / KITERS;   // 8334
    int blocks = (waves_needed + 3) / 4;                    // 2084
    int total_waves = blocks * 4;                           // 8336

    iou_kernel<<<blocks, 256, 0, stream>>>(lhs, rhs, out, n_blocks, total_waves);
}